// Round 1
// baseline (55.907 us; speedup 1.0000x reference)
//
#include <hip/hip_runtime.h>

#define NN 4096
#define TT 365
#define CC 32
#define RPB 8          // rows (samples n) per block
#define BLOCK 384      // 6 waves; threads 0..364 map to t

// Workspace layout (doubles):
// [0..TT)           cls sums (sum over n of -logp[n,t,y])
// [TT]              earliness sum (over all n,t)
// [TT+1        .. TT+1+CC)    A[c] = sum e
// [TT+1+CC     .. TT+1+2CC)   B[c] = sum e*tf
// [TT+1+2CC    .. TT+1+3CC)   D[c] = sum e*tf*tf
#define WS_DOUBLES (TT + 1 + 3 * CC)

__global__ __launch_bounds__(BLOCK) void stp_main(
    const float* __restrict__ logp,   // (N,T,C)
    const float* __restrict__ tl,     // (N,T)
    const int* __restrict__ yt,       // (N,T), constant per row
    double* __restrict__ ws)
{
    __shared__ int s_tmin[RPB];
    __shared__ double s_red[BLOCK / 64];

    const int tid = threadIdx.x;
    if (tid < RPB) s_tmin[tid] = TT - 1;  // last t always has tl==0
    __syncthreads();

    const int n0 = blockIdx.x * RPB;
    double cls_acc = 0.0;
    double earl_acc = 0.0;

    const float wt = 1.0f - (float)tid * (1.0f / 365.0f);  // (1 - t/T)

    if (tid < TT) {
        #pragma unroll
        for (int r = 0; r < RPB; ++r) {
            const int n = n0 + r;
            const int label = yt[(size_t)n * TT];          // uniform -> s_load
            const size_t nt = (size_t)n * TT + tid;
            const float lp  = logp[nt * CC + label];       // the gather
            const float tlv = tl[nt];
            cls_acc += (double)(-lp);
            const float pc = expf(lp);
            earl_acc += (double)(pc * wt * (1.0f - tlv * (1.0f / 365.0f)));
            if (tlv == 0.0f) atomicMin(&s_tmin[r], tid);
        }
    }
    __syncthreads();

    // per-t classification partial -> global (f64)
    if (tid < TT) atomicAdd(&ws[tid], cls_acc);

    // earliness: wave shuffle-reduce (f64), then cross-wave via LDS, one atomic
    for (int off = 32; off > 0; off >>= 1)
        earl_acc += __shfl_down(earl_acc, off, 64);
    const int wave = tid >> 6;
    if ((tid & 63) == 0) s_red[wave] = earl_acc;
    __syncthreads();
    if (tid == 0) {
        double s = 0.0;
        #pragma unroll
        for (int w = 0; w < BLOCK / 64; ++w) s += s_red[w];
        atomicAdd(&ws[TT], s);
    }

    // per-row stopping-time contribution to class moments A,B,D
    if (tid < RPB) {
        const int n = n0 + tid;
        const int tf = s_tmin[tid];
        const int label = yt[(size_t)n * TT];
        const float lp = logp[((size_t)n * TT + tf) * CC + label];
        const double e = (double)expf(lp);
        const double tfd = (double)tf;
        atomicAdd(&ws[TT + 1 + label],              e);
        atomicAdd(&ws[TT + 1 + CC + label],         e * tfd);
        atomicAdd(&ws[TT + 1 + 2 * CC + label],     e * tfd * tfd);
    }
}

__global__ __launch_bounds__(BLOCK) void stp_finalize(
    const double* __restrict__ ws, float* __restrict__ out)
{
    __shared__ double s_scalar;
    const int tid = threadIdx.x;
    if (tid == 0) {
        double p = 0.0;
        #pragma unroll
        for (int c = 0; c < CC; ++c) {
            const double A = ws[TT + 1 + c];
            const double B = ws[TT + 1 + CC + c];
            const double D = ws[TT + 1 + 2 * CC + c];
            p += A * D - B * B;
        }
        p /= (365.0 * 365.0);
        const double earl = ws[TT] / (double)NN;
        s_scalar = (1.0 / 3.0) * (earl + p);
    }
    __syncthreads();
    if (tid < TT) {
        const double cls = ws[tid] / (double)NN;
        out[tid] = (float)((1.0 / 3.0) * cls - s_scalar);
    }
}

extern "C" void kernel_launch(void* const* d_in, const int* in_sizes, int n_in,
                              void* d_out, int out_size, void* d_ws, size_t ws_size,
                              hipStream_t stream)
{
    const float* logp = (const float*)d_in[0];
    const float* tl   = (const float*)d_in[1];
    const int*   yt   = (const int*)d_in[2];
    float* out = (float*)d_out;
    double* ws = (double*)d_ws;

    hipMemsetAsync(ws, 0, WS_DOUBLES * sizeof(double), stream);
    stp_main<<<NN / RPB, BLOCK, 0, stream>>>(logp, tl, yt, ws);
    stp_finalize<<<1, BLOCK, 0, stream>>>(ws, out);
}

// Round 2
// 53.788 us; speedup vs baseline: 1.0394x; 1.0394x over previous
//
#include <hip/hip_runtime.h>

#define NN 4096
#define TT 365
#define CC 32
#define RPB 8          // rows per block -> grid = 512
#define BLOCK 512      // 8 waves
#define F4_PER_ROW (TT * CC / 4)   // 2920 float4 per row

// Workspace layout (doubles):
// [0..TT)    cls sums (sum over n of -logp[n,t,y])
// [TT]       earliness sum (over all n,t)
// [TT+1        .. TT+1+CC)   A[c] = sum e
// [TT+1+CC     .. TT+1+2CC)  B[c] = sum e*tf
// [TT+1+2CC    .. TT+1+3CC)  D[c] = sum e*tf*tf
#define WS_DOUBLES (TT + 1 + 3 * CC)

__global__ __launch_bounds__(BLOCK) void stp_main(
    const float4* __restrict__ logp4,  // (N, T, C/4)
    const float* __restrict__ tl,      // (N, T) -- only column 0 is read
    const int* __restrict__ yt,        // (N, T) -- only column 0 is read
    double* __restrict__ ws)
{
    __shared__ float  s_cls[TT];
    __shared__ double s_red[BLOCK / 64];
    __shared__ int    s_label[RPB];
    __shared__ float  s_tf[RPB];

    const int tid = threadIdx.x;
    const int n0 = blockIdx.x * RPB;

    for (int i = tid; i < TT; i += BLOCK) s_cls[i] = 0.0f;
    if (tid < RPB) {
        const size_t base = (size_t)(n0 + tid) * TT;
        s_label[tid] = yt[base];
        s_tf[tid]    = tl[base];   // tl[n,0] = lengths-1 = t_final (exact int)
    }
    __syncthreads();

    double earl = 0.0;
    const float invT = 1.0f / 365.0f;

    for (int r = 0; r < RPB; ++r) {
        const int   label = s_label[r];
        const float tf_f  = s_tf[r];
        const int   j0    = label >> 2;   // owning float4 chunk within the cell
        const int   c0    = label & 3;    // component within that float4
        const float4* row = logp4 + (size_t)(n0 + r) * F4_PER_ROW;

        for (int i = tid; i < F4_PER_ROW; i += BLOCK) {
            const float4 v = row[i];      // fully coalesced dense read
            if ((i & 7) == j0) {          // this lane owns cell t = i>>3
                const int t = i >> 3;
                const float lp = (c0 & 2) ? ((c0 & 1) ? v.w : v.z)
                                          : ((c0 & 1) ? v.y : v.x);
                atomicAdd(&s_cls[t], -lp);
                const float pc  = expf(lp);
                const float tlv = fmaxf(tf_f - (float)t, 0.0f);
                earl += (double)(pc * (1.0f - (float)t * invT)
                                    * (1.0f - tlv * invT));
                if ((float)t == tf_f) {   // stopping-time cell: proximity moments
                    const double e   = (double)pc;
                    const double tfd = (double)t;
                    atomicAdd(&ws[TT + 1 + label],           e);
                    atomicAdd(&ws[TT + 1 + CC + label],      e * tfd);
                    atomicAdd(&ws[TT + 1 + 2 * CC + label],  e * tfd * tfd);
                }
            }
        }
    }

    // earliness: wave shuffle-reduce (f64) -> cross-wave LDS -> one atomic
    for (int off = 32; off > 0; off >>= 1)
        earl += __shfl_down(earl, off, 64);
    if ((tid & 63) == 0) s_red[tid >> 6] = earl;
    __syncthreads();
    if (tid == 0) {
        double s = 0.0;
        #pragma unroll
        for (int w = 0; w < BLOCK / 64; ++w) s += s_red[w];
        atomicAdd(&ws[TT], s);
    }

    // flush per-block cls partials (f64 accumulation globally)
    for (int i = tid; i < TT; i += BLOCK)
        atomicAdd(&ws[i], (double)s_cls[i]);
}

__global__ __launch_bounds__(BLOCK) void stp_finalize(
    const double* __restrict__ ws, float* __restrict__ out)
{
    __shared__ double s_scalar;
    const int tid = threadIdx.x;
    if (tid == 0) {
        double p = 0.0;
        #pragma unroll
        for (int c = 0; c < CC; ++c) {
            const double A = ws[TT + 1 + c];
            const double B = ws[TT + 1 + CC + c];
            const double D = ws[TT + 1 + 2 * CC + c];
            p += A * D - B * B;
        }
        p /= (365.0 * 365.0);
        const double e = ws[TT] / (double)NN;
        s_scalar = (1.0 / 3.0) * (e + p);
    }
    __syncthreads();
    if (tid < TT) {
        const double cls = ws[tid] / (double)NN;
        out[tid] = (float)((1.0 / 3.0) * cls - s_scalar);
    }
}

extern "C" void kernel_launch(void* const* d_in, const int* in_sizes, int n_in,
                              void* d_out, int out_size, void* d_ws, size_t ws_size,
                              hipStream_t stream)
{
    const float4* logp4 = (const float4*)d_in[0];
    const float*  tl    = (const float*)d_in[1];
    const int*    yt    = (const int*)d_in[2];
    float* out = (float*)d_out;
    double* ws = (double*)d_ws;

    hipMemsetAsync(ws, 0, WS_DOUBLES * sizeof(double), stream);
    stp_main<<<NN / RPB, BLOCK, 0, stream>>>(logp4, tl, yt, ws);
    stp_finalize<<<1, BLOCK, 0, stream>>>(ws, out);
}